// Round 3
// baseline (934.990 us; speedup 1.0000x reference)
//
#include <hip/hip_runtime.h>

#define L_ 2048
#define H_ 8

typedef __attribute__((ext_vector_type(8))) short short8;
typedef __attribute__((ext_vector_type(4))) float f32x4;

static constexpr size_t OFF_S = 2097152;            // B*L*H*D
static constexpr size_t OFF_P = OFF_S + 67108864;   // + B*H*L*L
static constexpr size_t OFF_G = OFF_P + 67108864;

// ws layout (bytes): inv_l at 0; K tiles at 1 MB; V tiles at 5 MB; bf16 p at 16 MB (134 MB)
static constexpr size_t WS_K = 1u << 20;
static constexpr size_t WS_V = WS_K + (4u << 20);
static constexpr size_t WS_P = 16u << 20;

__device__ __forceinline__ unsigned short f2bf(float x) {
    union { float f; unsigned int u; } c; c.f = x;
    unsigned int u = c.u;
    u += 0x7fffu + ((u >> 16) & 1u);               // RNE
    return (unsigned short)(u >> 16);
}
__device__ __forceinline__ float bf2f(unsigned short u) {
    union { float f; unsigned int v; } c; c.v = ((unsigned int)u) << 16; return c.f;
}

__device__ __forceinline__ void gld_lds16(const unsigned short* g, unsigned short* l) {
    __builtin_amdgcn_global_load_lds(
        (const __attribute__((address_space(1))) void*)g,
        (__attribute__((address_space(3))) void*)l, 16, 0, 0);
}

// ===== kernel 0: K -> bf16 swizzled tiles; V -> bf16 transposed swizzled tiles =====
// tile image: 64 rows x 64 bf16; element (r, chunk c) at r*64 + (c ^ (r&7))*8 shorts.
__global__ __launch_bounds__(256) void prep(
    const float* __restrict__ k, const float* __restrict__ v,
    unsigned short* __restrict__ wsK, unsigned short* __restrict__ wsV)
{
    const int tid = threadIdx.x;
    const int blk = blockIdx.x;
    __shared__ __attribute__((aligned(16))) unsigned short tr[64][72];
    if (blk < 512) {                                 // K path: (bh, t)
        const int bh = blk >> 5, t = blk & 31;
        const int b = bh >> 3, h = bh & 7;
        unsigned short* dst = wsK + (size_t)(bh * 32 + t) * 4096;
        #pragma unroll
        for (int p = 0; p < 2; ++p) {
            const int cid = tid + (p << 8);
            const int r = cid >> 3, c = cid & 7;
            const int j = (t << 6) + r;
            const float4* src = reinterpret_cast<const float4*>(
                k + (((size_t)((b * L_ + j) * H_ + h)) << 6) + (c << 3));
            float4 x0 = src[0], x1 = src[1];
            union { short8 s; unsigned short u[8]; } w;
            w.u[0]=f2bf(x0.x); w.u[1]=f2bf(x0.y); w.u[2]=f2bf(x0.z); w.u[3]=f2bf(x0.w);
            w.u[4]=f2bf(x1.x); w.u[5]=f2bf(x1.y); w.u[6]=f2bf(x1.z); w.u[7]=f2bf(x1.w);
            *reinterpret_cast<short8*>(dst + r * 64 + ((c ^ (r & 7)) << 3)) = w.s;
        }
    } else {                                         // V path: transpose via LDS
        const int vb = blk - 512;
        const int bh = vb >> 5, t = vb & 31;
        const int b = bh >> 3, h = bh & 7;
        const int col4 = (tid & 15) << 2;
        #pragma unroll
        for (int p = 0; p < 4; ++p) {
            const int r = (tid >> 4) + (p << 4);
            const int j = (t << 6) + r;
            float4 x = *reinterpret_cast<const float4*>(
                v + (((size_t)((b * L_ + j) * H_ + h)) << 6) + col4);
            tr[col4 + 0][r] = f2bf(x.x); tr[col4 + 1][r] = f2bf(x.y);
            tr[col4 + 2][r] = f2bf(x.z); tr[col4 + 3][r] = f2bf(x.w);
        }
        __syncthreads();
        unsigned short* dst = wsV + (size_t)(bh * 32 + t) * 4096;
        #pragma unroll
        for (int p = 0; p < 2; ++p) {
            const int cid = tid + (p << 8);
            const int d = cid >> 3, cj = cid & 7;
            short8 s = *reinterpret_cast<const short8*>(&tr[d][cj << 3]);
            *reinterpret_cast<short8*>(dst + d * 64 + ((cj ^ (d & 7)) << 3)) = s;
        }
    }
}

// ===== kernel 1: single-pass attention, 32 query rows/block =====
__global__ __launch_bounds__(256) void attn(
    const float* __restrict__ q,
    const unsigned short* __restrict__ wsK, const unsigned short* __restrict__ wsV,
    float* __restrict__ out, float* __restrict__ ws_inv, unsigned short* __restrict__ wsP)
{
    __shared__ __attribute__((aligned(16))) unsigned short Kb[2][4096];
    __shared__ __attribute__((aligned(16))) unsigned short Vb[2][4096];
    __shared__ __attribute__((aligned(16))) unsigned short Pt[32][72];
    __shared__ float l_sums[32];

    const int tid  = threadIdx.x;
    const int wv   = tid >> 6;
    const int lane = tid & 63;
    const int quad = lane >> 4;
    const int l16  = lane & 15;

    const int blk = blockIdx.x;
    // strip pairing: first 512 blocks take heavy strips (63..32), next 512 light (0..31)
    // -> each CU's resident set sums to ~constant tile count
    const int s   = (blk < 512) ? (63 - (blk >> 4)) : ((blk - 512) >> 4);
    const int bh  = blk & 15;
    const int b   = bh >> 3, h = bh & 7;
    const int i0  = s << 5;

    if (tid < 32) l_sums[tid] = 0.0f;
    __syncthreads();

    // Q A-fragments for both 16-row halves
    short8 a0l, a1l, a0h, a1h;
    {
        const float* qr = q + (((size_t)((b * L_ + (i0 + l16)) * H_ + h)) << 6);
        const float4* q4 = reinterpret_cast<const float4*>(qr) + quad * 2;
        float4 x0 = q4[0], x1 = q4[1], y0 = q4[8], y1 = q4[9];
        union { short8 v8; unsigned short u[8]; } fa, fb;
        fa.u[0]=f2bf(x0.x); fa.u[1]=f2bf(x0.y); fa.u[2]=f2bf(x0.z); fa.u[3]=f2bf(x0.w);
        fa.u[4]=f2bf(x1.x); fa.u[5]=f2bf(x1.y); fa.u[6]=f2bf(x1.z); fa.u[7]=f2bf(x1.w);
        fb.u[0]=f2bf(y0.x); fb.u[1]=f2bf(y0.y); fb.u[2]=f2bf(y0.z); fb.u[3]=f2bf(y0.w);
        fb.u[4]=f2bf(y1.x); fb.u[5]=f2bf(y1.y); fb.u[6]=f2bf(y1.z); fb.u[7]=f2bf(y1.w);
        a0l = fa.v8; a1l = fb.v8;
        const float* qr2 = qr + (16ll * H_ << 6);
        const float4* q42 = reinterpret_cast<const float4*>(qr2) + quad * 2;
        x0 = q42[0]; x1 = q42[1]; y0 = q42[8]; y1 = q42[9];
        fa.u[0]=f2bf(x0.x); fa.u[1]=f2bf(x0.y); fa.u[2]=f2bf(x0.z); fa.u[3]=f2bf(x0.w);
        fa.u[4]=f2bf(x1.x); fa.u[5]=f2bf(x1.y); fa.u[6]=f2bf(x1.z); fa.u[7]=f2bf(x1.w);
        fb.u[0]=f2bf(y0.x); fb.u[1]=f2bf(y0.y); fb.u[2]=f2bf(y0.z); fb.u[3]=f2bf(y0.w);
        fb.u[4]=f2bf(y1.x); fb.u[5]=f2bf(y1.y); fb.u[6]=f2bf(y1.z); fb.u[7]=f2bf(y1.w);
        a0h = fa.v8; a1h = fb.v8;
    }

    const int ntiles = (s >> 1) + 1;
    const unsigned short* gK = wsK + ((size_t)bh << 17);
    const unsigned short* gV = wsV + ((size_t)bh << 17);

    #define STAGE(buf, t) do {                                              \
        const unsigned short* _sk = gK + ((size_t)(t) << 12);               \
        const unsigned short* _sv = gV + ((size_t)(t) << 12);               \
        _Pragma("unroll")                                                   \
        for (int _qq = 0; _qq < 2; ++_qq) {                                 \
            const int _off = (wv << 10) + (_qq << 9);                       \
            gld_lds16(_sk + _off + (lane << 3), &Kb[buf][_off]);            \
            gld_lds16(_sv + _off + (lane << 3), &Vb[buf][_off]);            \
        }                                                                   \
    } while (0)

    f32x4 oacc0 = {0.f,0.f,0.f,0.f}, oacc1 = {0.f,0.f,0.f,0.f};
    float lp[8];
    #pragma unroll
    for (int z = 0; z < 8; ++z) lp[z] = 0.f;
    const int r  = (wv << 4) + l16;                  // j-row within tile (B-frag row)
    const int xr = r & 7;

    STAGE(0, 0);
    for (int t = 0; t < ntiles; ++t) {
        const int p = t & 1;
        // top barrier: drain only the staging DMAs (4 oldest); the p-store may stay in flight
        if (t == 0) asm volatile("s_waitcnt vmcnt(0)\n\ts_barrier" ::: "memory");
        else        asm volatile("s_waitcnt vmcnt(1)\n\ts_barrier" ::: "memory");
        if (t + 1 < ntiles) STAGE(1 - p, t + 1);     // DMA stays in flight through BOTH halves
        const int j0 = t << 6;
        const unsigned short* kb = &Kb[p][r << 6];
        short8 b0 = *reinterpret_cast<const short8*>(kb + ((quad ^ xr) << 3));
        short8 b1 = *reinterpret_cast<const short8*>(kb + (((quad + 4) ^ xr) << 3));
        const int j = j0 + r;
        #pragma unroll
        for (int g = 0; g < 2; ++g) {
            f32x4 c4 = {0.f,0.f,0.f,0.f};
            c4 = __builtin_amdgcn_mfma_f32_16x16x32_bf16(g ? a0h : a0l, b0, c4, 0, 0, 0);
            c4 = __builtin_amdgcn_mfma_f32_16x16x32_bf16(g ? a1h : a1l, b1, c4, 0, 0, 0);
            #pragma unroll
            for (int rr = 0; rr < 4; ++rr) {
                const int i = i0 + (g << 4) + (quad << 2) + rr;
                float pv = (j <= i) ? __expf(c4[rr] * 0.125f - 8.0f) : 0.0f;
                lp[(g << 2) + rr] += pv;
                Pt[(g << 4) + (quad << 2) + rr][r] = f2bf(pv);
            }
        }
        // mid barrier: LDS visibility only — does NOT drain the staging DMA
        asm volatile("s_waitcnt lgkmcnt(0)\n\ts_barrier" ::: "memory");
        const unsigned short* vb = &Vb[p][r << 6];
        short8 vb0 = *reinterpret_cast<const short8*>(vb + ((quad ^ xr) << 3));
        short8 vb1 = *reinterpret_cast<const short8*>(vb + (((quad + 4) ^ xr) << 3));
        short8 pa0l = *reinterpret_cast<const short8*>(&Pt[l16][quad << 3]);
        short8 pa1l = *reinterpret_cast<const short8*>(&Pt[l16][32 + (quad << 3)]);
        short8 pa0h = *reinterpret_cast<const short8*>(&Pt[16 + l16][quad << 3]);
        short8 pa1h = *reinterpret_cast<const short8*>(&Pt[16 + l16][32 + (quad << 3)]);
        oacc0 = __builtin_amdgcn_mfma_f32_16x16x32_bf16(pa0l, vb0, oacc0, 0, 0, 0);
        oacc0 = __builtin_amdgcn_mfma_f32_16x16x32_bf16(pa1l, vb1, oacc0, 0, 0, 0);
        oacc1 = __builtin_amdgcn_mfma_f32_16x16x32_bf16(pa0h, vb0, oacc1, 0, 0, 0);
        oacc1 = __builtin_amdgcn_mfma_f32_16x16x32_bf16(pa1h, vb1, oacc1, 0, 0, 0);
        // unnormalized p -> ws as raw bf16 (no conversion; 16B/lane coalesced)
        const int srow = tid >> 3, scol = (tid & 7) << 3;
        short8 sv = *reinterpret_cast<const short8*>(&Pt[srow][scol]);
        *reinterpret_cast<short8*>(wsP + (((size_t)(bh * L_ + i0 + srow)) << 11) + j0 + scol) = sv;
    }
    #undef STAGE

    #pragma unroll
    for (int z = 0; z < 8; ++z) {
        float x = lp[z];
        x += __shfl_xor(x, 1); x += __shfl_xor(x, 2);
        x += __shfl_xor(x, 4); x += __shfl_xor(x, 8);
        if (l16 == 0) atomicAdd(&l_sums[((z >> 2) << 4) + (quad << 2) + (z & 3)], x);
    }
    __syncthreads();
    #pragma unroll
    for (int z = 0; z < 8; ++z) {
        const int g = z >> 2, rr = z & 3;
        const int row = (g << 4) + (quad << 2) + rr;
        const int i = i0 + row;
        const float inv = 1.0f / l_sums[row];
        const float ov = (g ? oacc1[rr] : oacc0[rr]) * inv;
        out[(((size_t)((b * L_ + i) * H_ + h)) << 6) + (wv << 4) + l16] = ov;
    }
    if (tid < 32) ws_inv[(bh << 11) + i0 + tid] = 1.0f / l_sums[tid];
}

// ===== kernel 2: streaming — normalized series, prior, sigma_out (8 rows/block) =====
__global__ __launch_bounds__(256) void finish(
    const float* __restrict__ sg, const float* __restrict__ ws_inv,
    const unsigned short* __restrict__ wsP, float* __restrict__ out)
{
    __shared__ float sA[8], sC2[8], sS[8], sI[8];
    const int tid = threadIdx.x;
    const int g0 = blockIdx.x << 3;                  // g = bh*2048 + i
    if (tid < 8) {
        const int g = g0 + tid;
        const int bh = g >> 11, i = g & 2047, b = bh >> 3, h = bh & 7;
        const float x = sg[(size_t)((b * L_ + i) * H_ + h)];
        const float sgm = 1.0f / (1.0f + __expf(-5.0f * x)) + 1e-5f;
        const float sp = expm1f(sgm * 1.0986122886681098f);   // 3^sgm - 1
        sS[tid] = sp;
        sA[tid] = 0.3989422804014327f / sp;
        sC2[tid] = 0.5f / (sp * sp);
        sI[tid] = ws_inv[g];
    }
    __syncthreads();
    float* outS = out + OFF_S;
    float* outP = out + OFF_P;
    float* outG = out + OFF_G;
    const int c0 = tid << 3;
    #pragma unroll
    for (int rr = 0; rr < 8; ++rr) {
        const int g = g0 + rr;
        const int i = g & 2047;
        const size_t base = (size_t)g << 11;
        const float A = sA[rr], C2 = sC2[rr], S = sS[rr], I = sI[rr];
        union { short8 s; unsigned short u[8]; } pw;
        pw.s = *reinterpret_cast<const short8*>(wsP + base + c0);
        float4 s0, s1;
        s0.x = (c0 + 0 <= i) ? bf2f(pw.u[0]) * I : 0.f;
        s0.y = (c0 + 1 <= i) ? bf2f(pw.u[1]) * I : 0.f;
        s0.z = (c0 + 2 <= i) ? bf2f(pw.u[2]) * I : 0.f;
        s0.w = (c0 + 3 <= i) ? bf2f(pw.u[3]) * I : 0.f;
        s1.x = (c0 + 4 <= i) ? bf2f(pw.u[4]) * I : 0.f;
        s1.y = (c0 + 5 <= i) ? bf2f(pw.u[5]) * I : 0.f;
        s1.z = (c0 + 6 <= i) ? bf2f(pw.u[6]) * I : 0.f;
        s1.w = (c0 + 7 <= i) ? bf2f(pw.u[7]) * I : 0.f;
        *reinterpret_cast<float4*>(outS + base + c0)     = s0;
        *reinterpret_cast<float4*>(outS + base + c0 + 4) = s1;
        const float d0 = (float)(i - c0);
        float4 p0, p1;
        p0.x = A * __expf(-d0 * d0 * C2);
        { float d = d0 - 1.f; p0.y = A * __expf(-d * d * C2); }
        { float d = d0 - 2.f; p0.z = A * __expf(-d * d * C2); }
        { float d = d0 - 3.f; p0.w = A * __expf(-d * d * C2); }
        { float d = d0 - 4.f; p1.x = A * __expf(-d * d * C2); }
        { float d = d0 - 5.f; p1.y = A * __expf(-d * d * C2); }
        { float d = d0 - 6.f; p1.z = A * __expf(-d * d * C2); }
        { float d = d0 - 7.f; p1.w = A * __expf(-d * d * C2); }
        *reinterpret_cast<float4*>(outP + base + c0)     = p0;
        *reinterpret_cast<float4*>(outP + base + c0 + 4) = p1;
        float4 sv = {S, S, S, S};
        *reinterpret_cast<float4*>(outG + base + c0)     = sv;
        *reinterpret_cast<float4*>(outG + base + c0 + 4) = sv;
    }
}

extern "C" void kernel_launch(void* const* d_in, const int* in_sizes, int n_in,
                              void* d_out, int out_size, void* d_ws, size_t ws_size,
                              hipStream_t stream) {
    const float* q  = (const float*)d_in[0];
    const float* k  = (const float*)d_in[1];
    const float* v  = (const float*)d_in[2];
    const float* sg = (const float*)d_in[3];
    float* outp = (float*)d_out;
    float* ws_inv = (float*)d_ws;
    unsigned short* wsK = (unsigned short*)((char*)d_ws + WS_K);
    unsigned short* wsV = (unsigned short*)((char*)d_ws + WS_V);
    unsigned short* wsP = (unsigned short*)((char*)d_ws + WS_P);
    prep<<<dim3(1024), dim3(256), 0, stream>>>(k, v, wsK, wsV);
    attn<<<dim3(1024), dim3(256), 0, stream>>>(q, wsK, wsV, outp, ws_inv, wsP);
    finish<<<dim3(4096), dim3(256), 0, stream>>>(sg, ws_inv, wsP, outp);
}